// Round 1
// baseline (1465.015 us; speedup 1.0000x reference)
//
#include <hip/hip_runtime.h>
#include <math.h>

// Problem constants
#define T_SEQ 300
#define E_DIM 300
#define H_DIM 512
#define G4    2048          // 4*H
#define NEXPT 13
#define NBLK  256           // persistent blocks, block b owns cells {2b, 2b+1}

__device__ __forceinline__ float sigm(float x) { return 1.0f / (1.0f + __expf(-x)); }
__device__ __forceinline__ float ftanh(float x) {
  x = fminf(15.0f, fmaxf(-15.0f, x));
  float u = __expf(2.0f * x);
  return (u - 1.0f) / (u + 1.0f);
}

// ---------------------------------------------------------------------------
// Kernel 1: pre-gates. Expert-major so each W_ih row is loaded once per block
// and reused across that expert's timesteps.
// grid = 13 experts * 32 row-chunks (64 rows each), 256 threads.
// Thread = (row r_l in chunk [0..63], timestep slot s [0..3]): full 300-dot.
// Output layout matches the LSTM kernel's read: pg[t*2048 + b*8 + q*2 + p]
// where global row j = q*512 + 2b + p.
// ---------------------------------------------------------------------------
__global__ void __launch_bounds__(256) pregates_kernel(
    const int* __restrict__ x, const int* __restrict__ tags,
    const float* __restrict__ emb, const float* __restrict__ W_ih,
    const float* __restrict__ b_ih, const float* __restrict__ b_hh,
    float* __restrict__ pg)
{
  const int e     = blockIdx.x >> 5;   // expert 0..12
  const int chunk = blockIdx.x & 31;   // 0..31
  const int tid   = threadIdx.x;
  const int r_l   = tid & 63;
  const int s     = tid >> 6;          // 0..3
  const int row   = chunk * 64 + r_l;  // gate row 0..2047

  __shared__ int tags_l[T_SEQ];
  __shared__ int list[T_SEQ];
  __shared__ int nsh;
  __shared__ int xv[4];
  __shared__ __align__(16) float embL[4][E_DIM];

  for (int i = tid; i < T_SEQ; i += 256) tags_l[i] = tags[i];
  __syncthreads();
  if (tid == 0) {
    int n = 0;
    for (int t = 0; t < T_SEQ; ++t) if (tags_l[t] == e) list[n++] = t;
    nsh = n;
  }
  __syncthreads();
  const int n = nsh;
  const float bias = b_ih[e * G4 + row] + b_hh[e * G4 + row];
  const float4* wrow = (const float4*)(W_ih + ((size_t)e * G4 + row) * E_DIM);

  for (int it = 0; it < n; it += 4) {
    if (tid < 4 && it + tid < n) xv[tid] = x[list[it + tid]];
    __syncthreads();
    for (int idx = tid; idx < 4 * E_DIM; idx += 256) {
      int rs = idx / E_DIM, k = idx - rs * E_DIM;
      if (it + rs < n) embL[rs][k] = emb[(size_t)xv[rs] * E_DIM + k];
    }
    __syncthreads();
    if (it + s < n) {
      const float4* ev = (const float4*)embL[s];
      float4 acc4 = make_float4(0.f, 0.f, 0.f, 0.f);
      for (int k = 0; k < E_DIM / 4; ++k) {
        float4 w = wrow[k], a = ev[k];
        acc4.x += w.x * a.x; acc4.y += w.y * a.y;
        acc4.z += w.z * a.z; acc4.w += w.w * a.w;
      }
      float acc = acc4.x + acc4.y + acc4.z + acc4.w + bias;
      int t  = list[it + s];
      int oi = t * G4 + ((row & 511) >> 1) * 8 + (row >> 9) * 2 + (row & 1);
      pg[oi] = acc;
    }
    __syncthreads();
  }
}

// ---------------------------------------------------------------------------
// Kernel 2: persistent sequential LSTM. 256 blocks x 256 threads (cooperative).
// Block b owns cells {2b,2b+1} -> rows {q*512+2b+p} for q=0..3 (i,f,g,o).
// Thread = (row_local = tid>>5 in 0..7, lane_k = tid&31 covering 16 k each).
// Cross-block h exchange: 8B relaxed agent atomics packing (h_bits<<32)|step.
// No fences needed: the data rides inside the atomic. Double-buffered on t&1.
// c never leaves the owning block (lives in threads 0/1 registers).
// ---------------------------------------------------------------------------
__global__ void __launch_bounds__(256) lstm_kernel(
    const int* __restrict__ tags, const float* __restrict__ h0,
    const float* __restrict__ c0, const float* __restrict__ W_hh,
    const float* __restrict__ fc_w, const float* __restrict__ fc_b,
    const float* __restrict__ pg, unsigned long long* __restrict__ hbuf,
    float* __restrict__ out)
{
  const int b = blockIdx.x, tid = threadIdx.x;
  const int row_local = tid >> 5, lane_k = tid & 31;
  const int q = row_local >> 1, p = row_local & 1;
  const int rowG = q * H_DIM + 2 * b + p;

  __shared__ int tags_l[T_SEQ];
  __shared__ __align__(16) float h_lds[2][H_DIM];
  __shared__ float gates_l[8];
  __shared__ float red[4];

  for (int i = tid; i < T_SEQ; i += 256) tags_l[i] = tags[i];
  float c_r = 0.f, h_r = 0.f;
  if (tid < 2) c_r = c0[2 * b + tid];
  __syncthreads();

  for (int t = 0; t < T_SEQ; ++t) {
    const int e = tags_l[t];
    // Issue weight + pre-gate loads BEFORE polling: addresses depend only on
    // tags, so L2/L3 latency overlaps the spin-wait.
    const float4* wr = (const float4*)(W_hh + ((size_t)e * G4 + rowG) * H_DIM) + lane_k * 4;
    float4 w0 = wr[0], w1 = wr[1], w2 = wr[2], w3 = wr[3];
    float pgv = 0.0f;
    if (lane_k == 0) pgv = pg[t * G4 + b * 8 + row_local];

    float* hl = h_lds[t & 1];
    if (t == 0) {
      ((float2*)hl)[tid] = ((const float2*)h0)[tid];
    } else {
      unsigned long long* src = hbuf + (size_t)((t - 1) & 1) * H_DIM + 2 * tid;
      const unsigned tag = (unsigned)t;
      unsigned long long v0, v1;
      do { v0 = __hip_atomic_load(src,     __ATOMIC_RELAXED, __HIP_MEMORY_SCOPE_AGENT); } while ((unsigned)v0 != tag);
      do { v1 = __hip_atomic_load(src + 1, __ATOMIC_RELAXED, __HIP_MEMORY_SCOPE_AGENT); } while ((unsigned)v1 != tag);
      hl[2 * tid]     = __uint_as_float((unsigned)(v0 >> 32));
      hl[2 * tid + 1] = __uint_as_float((unsigned)(v1 >> 32));
    }
    __syncthreads();   // barrier A: h staged

    const float4* hv = (const float4*)hl + lane_k * 4;
    float4 a0 = hv[0], a1 = hv[1], a2 = hv[2], a3 = hv[3];
    float acc = w0.x*a0.x + w0.y*a0.y + w0.z*a0.z + w0.w*a0.w
              + w1.x*a1.x + w1.y*a1.y + w1.z*a1.z + w1.w*a1.w
              + w2.x*a2.x + w2.y*a2.y + w2.z*a2.z + w2.w*a2.w
              + w3.x*a3.x + w3.y*a3.y + w3.z*a3.z + w3.w*a3.w;
    #pragma unroll
    for (int m = 16; m >= 1; m >>= 1) acc += __shfl_xor(acc, m, 32);
    if (lane_k == 0) gates_l[row_local] = acc + pgv;
    __syncthreads();   // barrier B: gates ready

    if (tid < 2) {
      float iv = sigm(gates_l[0 + tid]);
      float fv = sigm(gates_l[2 + tid]);
      float gv = ftanh(gates_l[4 + tid]);
      float ov = sigm(gates_l[6 + tid]);
      c_r = fv * c_r + iv * gv;
      h_r = ov * ftanh(c_r);
      unsigned long long pv =
          ((unsigned long long)__float_as_uint(h_r) << 32) | (unsigned)(t + 1);
      __hip_atomic_store(hbuf + (size_t)(t & 1) * H_DIM + 2 * b + tid, pv,
                         __ATOMIC_RELAXED, __HIP_MEMORY_SCOPE_AGENT);
    }
    // No loop-end barrier needed: h_lds is parity double-buffered and barrier
    // A/B bound intra-block skew to < 1 step.
  }

  if (tid < 2) {
    out[1   + 2 * b + tid] = h_r;   // h slice
    out[513 + 2 * b + tid] = c_r;   // c slice
  }

  if (b == 0) {  // final scalar: sigmoid(h . fc_w + fc_b)
    unsigned long long* src = hbuf + (size_t)((T_SEQ - 1) & 1) * H_DIM + 2 * tid;
    unsigned long long v0, v1;
    do { v0 = __hip_atomic_load(src,     __ATOMIC_RELAXED, __HIP_MEMORY_SCOPE_AGENT); } while ((unsigned)v0 != (unsigned)T_SEQ);
    do { v1 = __hip_atomic_load(src + 1, __ATOMIC_RELAXED, __HIP_MEMORY_SCOPE_AGENT); } while ((unsigned)v1 != (unsigned)T_SEQ);
    float hv0 = __uint_as_float((unsigned)(v0 >> 32));
    float hv1 = __uint_as_float((unsigned)(v1 >> 32));
    float a = hv0 * fc_w[2 * tid] + hv1 * fc_w[2 * tid + 1];
    #pragma unroll
    for (int m = 32; m >= 1; m >>= 1) a += __shfl_xor(a, m, 64);
    if ((tid & 63) == 0) red[tid >> 6] = a;
    __syncthreads();
    if (tid == 0) out[0] = sigm(red[0] + red[1] + red[2] + red[3] + fc_b[0]);
  }
}

// ---------------------------------------------------------------------------
extern "C" void kernel_launch(void* const* d_in, const int* in_sizes, int n_in,
                              void* d_out, int out_size, void* d_ws, size_t ws_size,
                              hipStream_t stream) {
  const int*   x    = (const int*)d_in[0];
  const int*   tags = (const int*)d_in[1];
  const float* h0   = (const float*)d_in[2];
  const float* c0   = (const float*)d_in[3];
  const float* emb  = (const float*)d_in[4];
  const float* W_ih = (const float*)d_in[5];
  const float* W_hh = (const float*)d_in[6];
  const float* b_ih = (const float*)d_in[7];
  const float* b_hh = (const float*)d_in[8];
  const float* fc_w = (const float*)d_in[9];
  const float* fc_b = (const float*)d_in[10];
  float* out = (float*)d_out;

  // Workspace layout: pre-gates (300*2048 fp32 = 2.4 MB), then h exchange
  // buffer (2*512 u64). Poisoned 0xAA each launch == invalid tag, by design.
  float* pg = (float*)d_ws;
  unsigned long long* hbuf =
      (unsigned long long*)((char*)d_ws + (size_t)T_SEQ * G4 * sizeof(float));

  pregates_kernel<<<dim3(NEXPT * 32), dim3(256), 0, stream>>>(
      x, tags, emb, W_ih, b_ih, b_hh, pg);

  void* args[] = { (void*)&tags, (void*)&h0, (void*)&c0, (void*)&W_hh,
                   (void*)&fc_w, (void*)&fc_b, (void*)&pg, (void*)&hbuf,
                   (void*)&out };
  hipLaunchCooperativeKernel((const void*)lstm_kernel, dim3(NBLK), dim3(256),
                             args, 0, stream);
}